// Round 8
// baseline (1079.239 us; speedup 1.0000x reference)
//
#include <hip/hip_runtime.h>
#include <hip/hip_bf16.h>
#include <math.h>

#define B_ 4
#define C_ 512
#define N_ 4096

typedef float f32x4 __attribute__((ext_vector_type(4)));
typedef float f32x16 __attribute__((ext_vector_type(16)));
typedef __bf16 bf16x8 __attribute__((ext_vector_type(8)));

#define AS1(p) ((const __attribute__((address_space(1))) unsigned int*)(p))
#define AS3(p) ((__attribute__((address_space(3))) unsigned int*)(p))

__device__ __forceinline__ unsigned short f2bf(float x){
    return __builtin_bit_cast(unsigned short, (__bf16)x);
}
__device__ __forceinline__ float bf2f(unsigned short b){
    unsigned u = ((unsigned)b)<<16;
    return __builtin_bit_cast(float, u);
}
__device__ __forceinline__ f32x4 mfma16(bf16x8 a, bf16x8 b, f32x4 c){
    return __builtin_amdgcn_mfma_f32_16x16x32_bf16(a, b, c, 0, 0, 0);
}
__device__ __forceinline__ f32x16 mfma32(bf16x8 a, bf16x8 b, f32x16 c){
    return __builtin_amdgcn_mfma_f32_32x32x16_bf16(a, b, c, 0, 0, 0);
}

// ---------------- weight fp32 -> bf16 hi/lo split ----------------
__global__ void split_w(const float* __restrict__ src, unsigned short* __restrict__ hi,
                        unsigned short* __restrict__ lo){
    const int i = (blockIdx.x*256 + threadIdx.x)*4;
    f32x4 v = *(const f32x4*)(src + i);
    ushort4 h, l;
    unsigned short t0=f2bf(v[0]); h.x=t0; l.x=f2bf(v[0]-bf2f(t0));
    unsigned short t1=f2bf(v[1]); h.y=t1; l.y=f2bf(v[1]-bf2f(t1));
    unsigned short t2=f2bf(v[2]); h.z=t2; l.z=f2bf(v[2]-bf2f(t2));
    unsigned short t3=f2bf(v[3]); h.w=t3; l.w=f2bf(v[3]-bf2f(t3));
    *(ushort4*)(hi + i) = h;
    *(ushort4*)(lo + i) = l;
}

// ---------------- GroupNorm: partial sums ----------------
__global__ void gn_part(const float* __restrict__ x, float2* __restrict__ part){
    const int bg = blockIdx.y, blk = blockIdx.x, t = threadIdx.x;
    const float* base = x + (size_t)bg*(256*4096) + (size_t)blk*16384;
    float s = 0.f, q = 0.f;
    for (int i=0;i<16;i++){
        f32x4 v = *(const f32x4*)(base + i*1024 + t*4);
        s += v[0]+v[1]+v[2]+v[3];
        q += v[0]*v[0]+v[1]*v[1]+v[2]*v[2]+v[3]*v[3];
    }
    #pragma unroll
    for (int o=32;o>0;o>>=1){ s += __shfl_down(s, o); q += __shfl_down(q, o); }
    __shared__ float as[4], aq[4];
    if ((t&63)==0){ as[t>>6]=s; aq[t>>6]=q; }
    __syncthreads();
    if (t==0)
        part[bg*64 + blk] = make_float2(as[0]+as[1]+as[2]+as[3], aq[0]+aq[1]+aq[2]+aq[3]);
}

__global__ void gn_fin(const float2* __restrict__ part, float2* __restrict__ stats){
    const int bg = blockIdx.x, t = threadIdx.x;
    float2 p = part[bg*64 + t];
    float s = p.x, q = p.y;
    #pragma unroll
    for (int o=32;o>0;o>>=1){ s += __shfl_down(s,o); q += __shfl_down(q,o); }
    if (t==0){
        const float inv = 1.0f/(256.f*4096.f);
        float mu = s*inv;
        float var = q*inv - mu*mu;
        stats[bg] = make_float2(mu, rsqrtf(var + 1e-6f));
    }
}

// ---- GN apply + transpose + hi/lo split: x[B][C][N] -> hT[B][N][C] (bf16 hi,lo) ----
__global__ void gn_apply(const float* __restrict__ x, const float* __restrict__ gw,
                         const float* __restrict__ gb, const float2* __restrict__ stats,
                         unsigned short* __restrict__ hTh, unsigned short* __restrict__ hTl)
{
    const int b = blockIdx.z, c0 = blockIdx.y*32, n0 = blockIdx.x*32;
    const int t = threadIdx.x;
    __shared__ float tile[32][37];
    {
        const int cl = t>>3, nl = (t&7)*4;
        const int c = c0 + cl;
        const float2 st = stats[b*2 + (c>>8)];
        const float wv = gw[c], bvv = gb[c];
        const f32x4 v = *(const f32x4*)(x + ((size_t)b*C_ + c)*N_ + n0 + nl);
        #pragma unroll
        for (int i=0;i<4;i++) tile[cl][nl+i] = (v[i] - st.x)*st.y*wv + bvv;
    }
    __syncthreads();
    {
        const int nl = t>>3, cl = (t&7)*4;
        const int n = n0 + nl;
        float f0 = tile[cl+0][nl], f1 = tile[cl+1][nl], f2 = tile[cl+2][nl], f3 = tile[cl+3][nl];
        unsigned short h0=f2bf(f0), h1=f2bf(f1), h2=f2bf(f2), h3=f2bf(f3);
        ushort4 hh, ll;
        hh.x=h0; hh.y=h1; hh.z=h2; hh.w=h3;
        ll.x=f2bf(f0-bf2f(h0)); ll.y=f2bf(f1-bf2f(h1));
        ll.z=f2bf(f2-bf2f(h2)); ll.w=f2bf(f3-bf2f(h3));
        size_t o = ((size_t)b*N_ + n)*C_ + c0 + cl;
        *(ushort4*)(hTh + o) = hh;
        *(ushort4*)(hTl + o) = ll;
    }
}

// ---------------- conv GEMM: out[o,n] = sum_c W[o,c]*S[c,n] + bias[o] ----------------
template<int PROD, int MODE>
__global__ __launch_bounds__(256, 2) void conv_gemm(
    const unsigned short* __restrict__ Wh, const unsigned short* __restrict__ Wl,
    const unsigned short* __restrict__ Sh, const unsigned short* __restrict__ Sl,
    const float* __restrict__ bias,
    unsigned short* __restrict__ outHi, unsigned short* __restrict__ outLo,
    float* __restrict__ outF, const float* __restrict__ resid)
{
    const int b = blockIdx.z, o0 = blockIdx.y*128, n0 = blockIdx.x*128;
    const int t = threadIdx.x, w = t>>6, l = t&63, lr = l&15, lg = l>>4;
    const int ro = (w>>1)*64, co = (w&1)*64;
    __shared__ unsigned short Ah[128][40];
    __shared__ unsigned short Al[128][40];
    __shared__ unsigned short Bh[128][40];
    __shared__ unsigned short Bl[128][40];
    f32x4 acc[4][4];
    #pragma unroll
    for (int i=0;i<4;i++)
        #pragma unroll
        for (int j=0;j<4;j++) acc[i][j] = (f32x4){0.f,0.f,0.f,0.f};

    const size_t srcB = (size_t)b*N_*C_;
    for (int ks=0; ks<16; ks++){
        const int c0 = ks*32;
        #pragma unroll
        for (int i=0;i<2;i++){
            int u = t + i*256;
            int row = u>>2, sch = (u&3)*8;
            *(bf16x8*)&Ah[row][sch] = *(const bf16x8*)(Wh + (size_t)(o0+row)*C_ + c0 + sch);
            *(bf16x8*)&Bh[row][sch] = *(const bf16x8*)(Sh + srcB + (size_t)(n0+row)*C_ + c0 + sch);
            if constexpr (PROD==3){
                *(bf16x8*)&Al[row][sch] = *(const bf16x8*)(Wl + (size_t)(o0+row)*C_ + c0 + sch);
                *(bf16x8*)&Bl[row][sch] = *(const bf16x8*)(Sl + srcB + (size_t)(n0+row)*C_ + c0 + sch);
            }
        }
        __syncthreads();
        bf16x8 af[4], bfv[4], afl[4], bfl[4];
        #pragma unroll
        for (int i=0;i<4;i++){
            af[i]  = *(const bf16x8*)&Ah[ro + i*16 + lr][lg*8];
            bfv[i] = *(const bf16x8*)&Bh[co + i*16 + lr][lg*8];
            if constexpr (PROD==3){
                afl[i] = *(const bf16x8*)&Al[ro + i*16 + lr][lg*8];
                bfl[i] = *(const bf16x8*)&Bl[co + i*16 + lr][lg*8];
            }
        }
        #pragma unroll
        for (int i=0;i<4;i++)
            #pragma unroll
            for (int j=0;j<4;j++){
                acc[i][j] = mfma16(af[i], bfv[j], acc[i][j]);
                if constexpr (PROD==3){
                    acc[i][j] = mfma16(af[i],  bfl[j], acc[i][j]);
                    acc[i][j] = mfma16(afl[i], bfv[j], acc[i][j]);
                }
            }
        __syncthreads();
    }
    #pragma unroll
    for (int i=0;i<4;i++){
        const int ob = o0 + ro + i*16 + lg*4;
        #pragma unroll
        for (int j=0;j<4;j++){
            const int n = n0 + co + j*16 + lr;
            f32x4 v = acc[i][j];
            if constexpr (MODE==0){
                float v0 = v[0] + bias[ob+0]; unsigned short h0 = f2bf(v0);
                float v1 = v[1] + bias[ob+1]; unsigned short h1 = f2bf(v1);
                float v2 = v[2] + bias[ob+2]; unsigned short h2 = f2bf(v2);
                float v3 = v[3] + bias[ob+3]; unsigned short h3 = f2bf(v3);
                ushort4 hh, ll;
                hh.x=h0; hh.y=h1; hh.z=h2; hh.w=h3;
                ll.x=f2bf(v0-bf2f(h0)); ll.y=f2bf(v1-bf2f(h1));
                ll.z=f2bf(v2-bf2f(h2)); ll.w=f2bf(v3-bf2f(h3));
                *(ushort4*)(outHi + srcB + (size_t)n*C_ + ob) = hh;
                *(ushort4*)(outLo + srcB + (size_t)n*C_ + ob) = ll;
            } else if constexpr (MODE==1){
                #pragma unroll
                for (int r=0;r<4;r++)
                    outHi[((size_t)b*C_ + ob + r)*N_ + n] = f2bf(v[r] + bias[ob+r]);
            } else {
                #pragma unroll
                for (int r=0;r<4;r++){
                    size_t idx = ((size_t)b*C_ + ob + r)*N_ + n;
                    outF[idx] = resid[idx] + v[r] + bias[ob+r];
                }
            }
        }
    }
}

// ------ flash attention v8: producer/consumer wave specialization, 32x32 MFMA ------
// 8 waves: w0-3 = QK producers (nh = w&1, ch = (w>>1)&1), one 32x32 S-frag each,
// K-hi from LDS (DMA dbuf), K-lo + Q-lo via global/registers, S^T -> Sb[ch][n][m].
// w4-7 = PV consumers (nh, cq): per-lane in-register softmax of row n=l&31, P packed
// directly into the PV A-frag, O accumulated in 8 f32x16 frags (32n x 256c).
// 2 barriers/tile, QK compute of tile t+1 overlaps PV softmax+PV of tile t.
__global__ __launch_bounds__(512, 2) void attn_flash8(
    const unsigned short* __restrict__ qTh, const unsigned short* __restrict__ qTl,
    const unsigned short* __restrict__ kTh, const unsigned short* __restrict__ kTl,
    const unsigned short* __restrict__ vB,  unsigned short* __restrict__ aoT)
{
    const int id = blockIdx.x;
    const int xcd = id & 7, slot = id >> 3;
    const int b = xcd >> 1;
    const int n0 = ((xcd & 1)*32 + slot)*64;
    const int t = threadIdx.x, w = t>>6, l = t&63, l31 = l&31, h = l>>5;
    const bool isQK = (w < 4);
    const int nh = isQK ? (w & 1) : ((w-4) & 1);
    const int ch = (w>>1) & 1;      // QK only
    const int cq = (w-4) >> 1;      // PV only

    __shared__ unsigned short khb[2][32*512];        // K-hi dbuf, xor-swizzled rows
    __shared__ __align__(16) float Sb[2][64][36];    // [ch-partial][n][m], stride 36
    __shared__ float rowFb[2][32], rowSb[2][32];

    // 128-VGPR shared state: QK = 32 q-fragments (hi 0-15, lo 16-31); PV = accO[8]
    f32x16 st[8];

    auto getq = [&](int s)->bf16x8{
        f32x4 tv; const int i = s>>2, j = (s&3)*4;
        tv[0]=st[i][j]; tv[1]=st[i][j+1]; tv[2]=st[i][j+2]; tv[3]=st[i][j+3];
        return __builtin_bit_cast(bf16x8, tv);
    };
    auto setq = [&](int s, bf16x8 v){
        f32x4 tv = __builtin_bit_cast(f32x4, v);
        const int i = s>>2, j = (s&3)*4;
        st[i][j]=tv[0]; st[i][j+1]=tv[1]; st[i][j+2]=tv[2]; st[i][j+3]=tv[3];
    };

    if (isQK){
        const size_t qr = ((size_t)b*N_ + n0 + nh*32 + l31)*C_ + ch*256 + h*8;
        #pragma unroll
        for (int ks=0; ks<16; ks++){
            setq(ks,      *(const bf16x8*)(qTh + qr + ks*16));
            setq(16+ks,   *(const bf16x8*)(qTl + qr + ks*16));
        }
    } else {
        #pragma unroll
        for (int f=0; f<8; f++) st[f] = (f32x16)0.0f;
    }

    const size_t kBase = (size_t)b*N_*1024;   // bytes (C_*2 per row)

    auto stage = [&](int mt, int bi){
        const size_t kb = kBase + (size_t)mt*32768;
        #pragma unroll
        for (int i=0;i<8;i++){
            const int row = w*8 + i;                       // w<4 -> rows 0..31
            const int colb = (l*16) ^ ((row&7)<<4);
            __builtin_amdgcn_global_load_lds(
                AS1((const char*)kTh + kb + (size_t)row*1024 + colb),
                AS3((char*)khb + bi*32768 + row*1024 + l*16), 16, 0, 0);
        }
    };

    f32x16 sres;
    auto qk_compute = [&](int kt){
        f32x16 s0 = (f32x16)0.0f, s1 = (f32x16)0.0f;
        const char* khB = (const char*)khb + (kt&1)*32768 + l31*1024;
        const int swz = (l31&7)<<4;
        const int cb0 = ch*512 + h*16;
        const char* klB = (const char*)kTl + kBase + (size_t)(kt*32 + l31)*1024 + cb0;
        #pragma unroll
        for (int ks=0; ks<8; ks++){
            {
                bf16x8 khf = *(const bf16x8*)(khB + ((cb0 + ks*32) ^ swz));
                bf16x8 klf = *(const bf16x8*)(klB + ks*32);
                s0 = mfma32(khf, getq(ks),    s0);
                s0 = mfma32(khf, getq(16+ks), s0);
                s0 = mfma32(klf, getq(ks),    s0);
            }
            {
                bf16x8 khf = *(const bf16x8*)(khB + ((cb0 + (ks+8)*32) ^ swz));
                bf16x8 klf = *(const bf16x8*)(klB + (ks+8)*32);
                s1 = mfma32(khf, getq(ks+8),  s1);
                s1 = mfma32(khf, getq(24+ks), s1);
                s1 = mfma32(klf, getq(ks+8),  s1);
            }
        }
        sres = s0 + s1;
    };
    auto write_S = [&](){
        #pragma unroll
        for (int q=0;q<4;q++){
            f32x4 v; v[0]=sres[q*4]; v[1]=sres[q*4+1]; v[2]=sres[q*4+2]; v[3]=sres[q*4+3];
            *(f32x4*)&Sb[ch][nh*32 + l31][q*8 + h*4] = v;
        }
    };

    const float SC2 = 32.6444625f;   // sqrt(512)*log2(e)
    float m_run = -INFINITY, s_run = 0.f;

    auto pv_iter = [&](int tt){
        float p[32];
        const float* s0r = &Sb[0][nh*32 + l31][0];
        const float* s1r = &Sb[1][nh*32 + l31][0];
        #pragma unroll
        for (int u=0;u<8;u++){
            f32x4 a = *(const f32x4*)(s0r + u*4);
            f32x4 c = *(const f32x4*)(s1r + u*4);
            #pragma unroll
            for (int i=0;i<4;i++) p[u*4+i] = (a[i]+c[i])*SC2;
        }
        float m8[16];
        #pragma unroll
        for (int i=0;i<16;i++) m8[i] = fmaxf(p[i], p[i+16]);
        #pragma unroll
        for (int i=0;i<8;i++)  m8[i] = fmaxf(m8[i], m8[i+8]);
        #pragma unroll
        for (int i=0;i<4;i++)  m8[i] = fmaxf(m8[i], m8[i+4]);
        float mx = fmaxf(fmaxf(m8[0],m8[1]), fmaxf(m8[2],m8[3]));
        const float mnew = fmaxf(m_run, mx);
        const float f = exp2f(m_run - mnew);
        m_run = mnew;
        #pragma unroll
        for (int i=0;i<32;i++) p[i] = exp2f(p[i] - mnew);
        float a8[16];
        #pragma unroll
        for (int i=0;i<16;i++) a8[i] = p[i] + p[i+16];
        #pragma unroll
        for (int i=0;i<8;i++)  a8[i] += a8[i+8];
        #pragma unroll
        for (int i=0;i<4;i++)  a8[i] += a8[i+4];
        const float ps = (a8[0]+a8[1]) + (a8[2]+a8[3]);
        s_run = s_run*f + ps;
        rowFb[nh][l31] = f;
        float fr[16];
        #pragma unroll
        for (int q=0;q<4;q++)
            #pragma unroll
            for (int i=0;i<4;i++)
                fr[q*4+i] = rowFb[nh][i + 8*q + 4*h];
        bool need = false;
        #pragma unroll
        for (int r=0;r<16;r++) need |= (fr[r] != 1.0f);
        if (__any(need)){
            #pragma unroll
            for (int f8=0; f8<8; f8++)
                #pragma unroll
                for (int r=0;r<16;r++) st[f8][r] *= fr[r];
        }
        bf16x8 pa0, pa1;
        #pragma unroll
        for (int j=0;j<8;j++){
            pa0[j] = (__bf16)p[h*8+j];
            pa1[j] = (__bf16)p[16+h*8+j];
        }
        const size_t vbase = ((size_t)b*C_ + cq*256 + l31)*N_ + tt*32 + h*8;
        #pragma unroll
        for (int f8=0; f8<8; f8++){
            const unsigned short* vp = vB + vbase + (size_t)f8*32*N_;
            bf16x8 v0 = *(const bf16x8*)(vp);
            bf16x8 v1 = *(const bf16x8*)(vp + 16);
            st[f8] = mfma32(pa0, v0, st[f8]);
            st[f8] = mfma32(pa1, v1, st[f8]);
        }
    };

    // ---------------- prologue ----------------
    if (isQK){ stage(0, 0); stage(1, 1); }
    asm volatile("s_waitcnt vmcnt(0)" ::: "memory");
    __builtin_amdgcn_s_barrier();
    if (isQK) qk_compute(0);
    __builtin_amdgcn_s_barrier();
    if (isQK) write_S();
    asm volatile("s_waitcnt lgkmcnt(0)" ::: "memory");
    __builtin_amdgcn_s_barrier();

    // ---------------- main loop ----------------
    for (int tt=0; tt<128; ++tt){
        if (isQK){
            if (tt < 126) stage(tt+2, tt&1);
            if (tt < 127) qk_compute(tt+1);
            asm volatile("s_waitcnt vmcnt(0)" ::: "memory");
        } else {
            pv_iter(tt);
        }
        __builtin_amdgcn_s_barrier();             // X: PV done reading Sb(tt)
        if (isQK && tt < 127) write_S();          // publish S(tt+1)
        asm volatile("s_waitcnt lgkmcnt(0)" ::: "memory");
        __builtin_amdgcn_s_barrier();             // Y
    }

    // ---------------- epilogue: PV waves write O ----------------
    if (!isQK){
        rowSb[nh][l31] = s_run;
        float inv[16];
        #pragma unroll
        for (int q=0;q<4;q++)
            #pragma unroll
            for (int i=0;i<4;i++)
                inv[q*4+i] = 1.0f / rowSb[nh][i + 8*q + 4*h];
        #pragma unroll
        for (int f8=0; f8<8; f8++)
            #pragma unroll
            for (int q=0;q<4;q++)
                #pragma unroll
                for (int i=0;i<4;i++){
                    const int nrow = i + 8*q + 4*h;
                    aoT[((size_t)b*N_ + n0 + nh*32 + nrow)*C_ + cq*256 + f8*32 + l31]
                        = f2bf(st[f8][q*4+i] * inv[q*4+i]);
                }
    }
}

extern "C" void kernel_launch(void* const* d_in, const int* in_sizes, int n_in,
                              void* d_out, int out_size, void* d_ws, size_t ws_size,
                              hipStream_t stream)
{
    const float* x   = (const float*)d_in[0];
    const float* gnw = (const float*)d_in[1];
    const float* gnb = (const float*)d_in[2];
    const float* wq  = (const float*)d_in[3];
    const float* bq  = (const float*)d_in[4];
    const float* wk  = (const float*)d_in[5];
    const float* bk  = (const float*)d_in[6];
    const float* wv  = (const float*)d_in[7];
    const float* bv  = (const float*)d_in[8];
    const float* wp  = (const float*)d_in[9];
    const float* bp  = (const float*)d_in[10];
    float* out = (float*)d_out;

    char* ws = (char*)d_ws;
    size_t off = 0;
    auto alloc = [&](size_t bytes)->char*{
        char* p = ws + off; off += (bytes + 255) & ~(size_t)255; return p;
    };
    const size_t WB = (size_t)C_*C_*2;
    const size_t TB = (size_t)B_*N_*C_*2;
    unsigned short* wqh = (unsigned short*)alloc(WB);
    unsigned short* wql = (unsigned short*)alloc(WB);
    unsigned short* wkh = (unsigned short*)alloc(WB);
    unsigned short* wkl = (unsigned short*)alloc(WB);
    unsigned short* wvh = (unsigned short*)alloc(WB);
    unsigned short* wvl = (unsigned short*)alloc(WB);
    unsigned short* wph = (unsigned short*)alloc(WB);
    unsigned short* wpl = (unsigned short*)alloc(WB);
    unsigned short* hTh = (unsigned short*)alloc(TB);
    unsigned short* hTl = (unsigned short*)alloc(TB);
    unsigned short* qTh = (unsigned short*)alloc(TB);
    unsigned short* qTl = (unsigned short*)alloc(TB);
    unsigned short* kTh = (unsigned short*)alloc(TB);
    unsigned short* kTl = (unsigned short*)alloc(TB);
    unsigned short* vb  = (unsigned short*)alloc(TB);
    unsigned short* ao  = (unsigned short*)alloc(TB);
    float2* part  = (float2*)alloc(8*64*sizeof(float2));
    float2* stats = (float2*)alloc(8*sizeof(float2));

    split_w<<<256, 256, 0, stream>>>(wq, wqh, wql);
    split_w<<<256, 256, 0, stream>>>(wk, wkh, wkl);
    split_w<<<256, 256, 0, stream>>>(wv, wvh, wvl);
    split_w<<<256, 256, 0, stream>>>(wp, wph, wpl);
    gn_part<<<dim3(64, 8), 256, 0, stream>>>(x, part);
    gn_fin<<<8, 64, 0, stream>>>(part, stats);
    gn_apply<<<dim3(128, 16, B_), 256, 0, stream>>>(x, gnw, gnb, stats, hTh, hTl);
    conv_gemm<3,0><<<dim3(32,4,B_), 256, 0, stream>>>(wqh,wql,hTh,hTl,bq, qTh,qTl,nullptr,nullptr);
    conv_gemm<3,0><<<dim3(32,4,B_), 256, 0, stream>>>(wkh,wkl,hTh,hTl,bk, kTh,kTl,nullptr,nullptr);
    conv_gemm<1,1><<<dim3(32,4,B_), 256, 0, stream>>>(wvh,wvl,hTh,hTl,bv, vb,nullptr,nullptr,nullptr);
    attn_flash8<<<dim3(256), 512, 0, stream>>>(qTh,qTl,kTh,kTl,vb,ao);
    conv_gemm<1,2><<<dim3(32,4,B_), 256, 0, stream>>>(wph,wpl,ao,nullptr,bp, nullptr,nullptr,out,x);
}

// Round 9
// 843.401 us; speedup vs baseline: 1.2796x; 1.2796x over previous
//
#include <hip/hip_runtime.h>
#include <hip/hip_bf16.h>
#include <math.h>

#define B_ 4
#define C_ 512
#define N_ 4096

typedef float f32x4 __attribute__((ext_vector_type(4)));
typedef float f32x16 __attribute__((ext_vector_type(16)));
typedef __bf16 bf16x8 __attribute__((ext_vector_type(8)));

#define AS1(p) ((const __attribute__((address_space(1))) unsigned int*)(p))
#define AS3(p) ((__attribute__((address_space(3))) unsigned int*)(p))

__device__ __forceinline__ unsigned short f2bf(float x){
    return __builtin_bit_cast(unsigned short, (__bf16)x);
}
__device__ __forceinline__ float bf2f(unsigned short b){
    unsigned u = ((unsigned)b)<<16;
    return __builtin_bit_cast(float, u);
}
__device__ __forceinline__ f32x4 mfma16(bf16x8 a, bf16x8 b, f32x4 c){
    return __builtin_amdgcn_mfma_f32_16x16x32_bf16(a, b, c, 0, 0, 0);
}
__device__ __forceinline__ f32x16 mfma32(bf16x8 a, bf16x8 b, f32x16 c){
    return __builtin_amdgcn_mfma_f32_32x32x16_bf16(a, b, c, 0, 0, 0);
}

// ---------------- weight fp32 -> bf16 hi/lo split ----------------
__global__ void split_w(const float* __restrict__ src, unsigned short* __restrict__ hi,
                        unsigned short* __restrict__ lo){
    const int i = (blockIdx.x*256 + threadIdx.x)*4;
    f32x4 v = *(const f32x4*)(src + i);
    ushort4 h, l;
    unsigned short t0=f2bf(v[0]); h.x=t0; l.x=f2bf(v[0]-bf2f(t0));
    unsigned short t1=f2bf(v[1]); h.y=t1; l.y=f2bf(v[1]-bf2f(t1));
    unsigned short t2=f2bf(v[2]); h.z=t2; l.z=f2bf(v[2]-bf2f(t2));
    unsigned short t3=f2bf(v[3]); h.w=t3; l.w=f2bf(v[3]-bf2f(t3));
    *(ushort4*)(hi + i) = h;
    *(ushort4*)(lo + i) = l;
}

// ---------------- GroupNorm: partial sums ----------------
__global__ void gn_part(const float* __restrict__ x, float2* __restrict__ part){
    const int bg = blockIdx.y, blk = blockIdx.x, t = threadIdx.x;
    const float* base = x + (size_t)bg*(256*4096) + (size_t)blk*16384;
    float s = 0.f, q = 0.f;
    for (int i=0;i<16;i++){
        f32x4 v = *(const f32x4*)(base + i*1024 + t*4);
        s += v[0]+v[1]+v[2]+v[3];
        q += v[0]*v[0]+v[1]*v[1]+v[2]*v[2]+v[3]*v[3];
    }
    #pragma unroll
    for (int o=32;o>0;o>>=1){ s += __shfl_down(s, o); q += __shfl_down(q, o); }
    __shared__ float as[4], aq[4];
    if ((t&63)==0){ as[t>>6]=s; aq[t>>6]=q; }
    __syncthreads();
    if (t==0)
        part[bg*64 + blk] = make_float2(as[0]+as[1]+as[2]+as[3], aq[0]+aq[1]+aq[2]+aq[3]);
}

__global__ void gn_fin(const float2* __restrict__ part, float2* __restrict__ stats){
    const int bg = blockIdx.x, t = threadIdx.x;
    float2 p = part[bg*64 + t];
    float s = p.x, q = p.y;
    #pragma unroll
    for (int o=32;o>0;o>>=1){ s += __shfl_down(s,o); q += __shfl_down(q,o); }
    if (t==0){
        const float inv = 1.0f/(256.f*4096.f);
        float mu = s*inv;
        float var = q*inv - mu*mu;
        stats[bg] = make_float2(mu, rsqrtf(var + 1e-6f));
    }
}

// ---- GN apply + transpose + hi/lo split: x[B][C][N] -> hT[B][N][C] (bf16 hi,lo) ----
__global__ void gn_apply(const float* __restrict__ x, const float* __restrict__ gw,
                         const float* __restrict__ gb, const float2* __restrict__ stats,
                         unsigned short* __restrict__ hTh, unsigned short* __restrict__ hTl)
{
    const int b = blockIdx.z, c0 = blockIdx.y*32, n0 = blockIdx.x*32;
    const int t = threadIdx.x;
    __shared__ float tile[32][37];
    {
        const int cl = t>>3, nl = (t&7)*4;
        const int c = c0 + cl;
        const float2 st = stats[b*2 + (c>>8)];
        const float wv = gw[c], bvv = gb[c];
        const f32x4 v = *(const f32x4*)(x + ((size_t)b*C_ + c)*N_ + n0 + nl);
        #pragma unroll
        for (int i=0;i<4;i++) tile[cl][nl+i] = (v[i] - st.x)*st.y*wv + bvv;
    }
    __syncthreads();
    {
        const int nl = t>>3, cl = (t&7)*4;
        const int n = n0 + nl;
        float f0 = tile[cl+0][nl], f1 = tile[cl+1][nl], f2 = tile[cl+2][nl], f3 = tile[cl+3][nl];
        unsigned short h0=f2bf(f0), h1=f2bf(f1), h2=f2bf(f2), h3=f2bf(f3);
        ushort4 hh, ll;
        hh.x=h0; hh.y=h1; hh.z=h2; hh.w=h3;
        ll.x=f2bf(f0-bf2f(h0)); ll.y=f2bf(f1-bf2f(h1));
        ll.z=f2bf(f2-bf2f(h2)); ll.w=f2bf(f3-bf2f(h3));
        size_t o = ((size_t)b*N_ + n)*C_ + c0 + cl;
        *(ushort4*)(hTh + o) = hh;
        *(ushort4*)(hTl + o) = ll;
    }
}

// ---------------- conv GEMM: out[o,n] = sum_c W[o,c]*S[c,n] + bias[o] ----------------
template<int PROD, int MODE>
__global__ __launch_bounds__(256, 2) void conv_gemm(
    const unsigned short* __restrict__ Wh, const unsigned short* __restrict__ Wl,
    const unsigned short* __restrict__ Sh, const unsigned short* __restrict__ Sl,
    const float* __restrict__ bias,
    unsigned short* __restrict__ outHi, unsigned short* __restrict__ outLo,
    float* __restrict__ outF, const float* __restrict__ resid)
{
    const int b = blockIdx.z, o0 = blockIdx.y*128, n0 = blockIdx.x*128;
    const int t = threadIdx.x, w = t>>6, l = t&63, lr = l&15, lg = l>>4;
    const int ro = (w>>1)*64, co = (w&1)*64;
    __shared__ unsigned short Ah[128][40];
    __shared__ unsigned short Al[128][40];
    __shared__ unsigned short Bh[128][40];
    __shared__ unsigned short Bl[128][40];
    f32x4 acc[4][4];
    #pragma unroll
    for (int i=0;i<4;i++)
        #pragma unroll
        for (int j=0;j<4;j++) acc[i][j] = (f32x4){0.f,0.f,0.f,0.f};

    const size_t srcB = (size_t)b*N_*C_;
    for (int ks=0; ks<16; ks++){
        const int c0 = ks*32;
        #pragma unroll
        for (int i=0;i<2;i++){
            int u = t + i*256;
            int row = u>>2, sch = (u&3)*8;
            *(bf16x8*)&Ah[row][sch] = *(const bf16x8*)(Wh + (size_t)(o0+row)*C_ + c0 + sch);
            *(bf16x8*)&Bh[row][sch] = *(const bf16x8*)(Sh + srcB + (size_t)(n0+row)*C_ + c0 + sch);
            if constexpr (PROD==3){
                *(bf16x8*)&Al[row][sch] = *(const bf16x8*)(Wl + (size_t)(o0+row)*C_ + c0 + sch);
                *(bf16x8*)&Bl[row][sch] = *(const bf16x8*)(Sl + srcB + (size_t)(n0+row)*C_ + c0 + sch);
            }
        }
        __syncthreads();
        bf16x8 af[4], bfv[4], afl[4], bfl[4];
        #pragma unroll
        for (int i=0;i<4;i++){
            af[i]  = *(const bf16x8*)&Ah[ro + i*16 + lr][lg*8];
            bfv[i] = *(const bf16x8*)&Bh[co + i*16 + lr][lg*8];
            if constexpr (PROD==3){
                afl[i] = *(const bf16x8*)&Al[ro + i*16 + lr][lg*8];
                bfl[i] = *(const bf16x8*)&Bl[co + i*16 + lr][lg*8];
            }
        }
        #pragma unroll
        for (int i=0;i<4;i++)
            #pragma unroll
            for (int j=0;j<4;j++){
                acc[i][j] = mfma16(af[i], bfv[j], acc[i][j]);
                if constexpr (PROD==3){
                    acc[i][j] = mfma16(af[i],  bfl[j], acc[i][j]);
                    acc[i][j] = mfma16(afl[i], bfv[j], acc[i][j]);
                }
            }
        __syncthreads();
    }
    #pragma unroll
    for (int i=0;i<4;i++){
        const int ob = o0 + ro + i*16 + lg*4;
        #pragma unroll
        for (int j=0;j<4;j++){
            const int n = n0 + co + j*16 + lr;
            f32x4 v = acc[i][j];
            if constexpr (MODE==0){
                float v0 = v[0] + bias[ob+0]; unsigned short h0 = f2bf(v0);
                float v1 = v[1] + bias[ob+1]; unsigned short h1 = f2bf(v1);
                float v2 = v[2] + bias[ob+2]; unsigned short h2 = f2bf(v2);
                float v3 = v[3] + bias[ob+3]; unsigned short h3 = f2bf(v3);
                ushort4 hh, ll;
                hh.x=h0; hh.y=h1; hh.z=h2; hh.w=h3;
                ll.x=f2bf(v0-bf2f(h0)); ll.y=f2bf(v1-bf2f(h1));
                ll.z=f2bf(v2-bf2f(h2)); ll.w=f2bf(v3-bf2f(h3));
                *(ushort4*)(outHi + srcB + (size_t)n*C_ + ob) = hh;
                *(ushort4*)(outLo + srcB + (size_t)n*C_ + ob) = ll;
            } else if constexpr (MODE==1){
                #pragma unroll
                for (int r=0;r<4;r++)
                    outHi[((size_t)b*C_ + ob + r)*N_ + n] = f2bf(v[r] + bias[ob+r]);
            } else {
                #pragma unroll
                for (int r=0;r<4;r++){
                    size_t idx = ((size_t)b*C_ + ob + r)*N_ + n;
                    outF[idx] = resid[idx] + v[r] + bias[ob+r];
                }
            }
        }
    }
}

// ------ flash attention v9: single barrier/tile, in-register softmax->PV ------
// QK role (R4-validated): wave = (fm2, fn, ch); q hi/lo in regs; K-hi via LDS DMA
// (dbuf), K-lo direct from global (L2). S written to parity-dbuf Sb[p][ch][n][m].
// PV role: wave = (nh = w&1, cq = w>>1); lane owns row n = nh*32 + (l&31);
// softmax fully in-lane (2 shuffles); P packed in-register as mfma32 B-frag;
// O^T = mfma32(V-frag, P); rescale/normalize are per-lane scalars. No Pb, no
// row-stat LDS, one barrier per tile.
__global__ __launch_bounds__(512, 2) void attn_flash9(
    const unsigned short* __restrict__ qTh, const unsigned short* __restrict__ qTl,
    const unsigned short* __restrict__ kTh, const unsigned short* __restrict__ kTl,
    const unsigned short* __restrict__ vB,  unsigned short* __restrict__ aoT)
{
    const int id = blockIdx.x;
    const int xcd = id & 7, slot = id >> 3;
    const int b = xcd >> 1;
    const int n0 = ((xcd & 1)*32 + slot)*64;
    const int t = threadIdx.x, w = t>>6, l = t&63;
    const int lr = l&15, lg = l>>4, l31 = l&31, h = l>>5;
    const int fm2 = w>>2, fn = (w>>1)&1, ch = w&1;   // QK role
    const int nh = w&1, cq = w>>1;                    // PV role

    __shared__ unsigned short khb[2][32*512];         // K-hi dbuf, row-XOR swizzled
    __shared__ float Sb[2][2][64][34];                // [parity][ch][n][m]

    // q fragments (R4 layout): rows n0+fm2*32+{0,16}+lr, c-half ch, hi+lo
    bf16x8 qh[2][8], ql[2][8];
    #pragma unroll
    for (int f=0; f<2; f++){
        const size_t qr = ((size_t)b*N_ + n0 + fm2*32 + f*16 + lr)*C_ + ch*256;
        #pragma unroll
        for (int kc=0; kc<8; kc++){
            qh[f][kc] = *(const bf16x8*)(qTh + qr + kc*32 + lg*8);
            ql[f][kc] = *(const bf16x8*)(qTl + qr + kc*32 + lg*8);
        }
    }
    f32x16 accO[4];
    #pragma unroll
    for (int i=0;i<4;i++) accO[i] = (f32x16)0.0f;
    float m_run = -INFINITY, s_run = 0.f;

    const size_t kBase = (size_t)b*N_*1024;           // bytes; C_*2 per row
    const float SC2 = 32.6444622284f;                 // sqrt(512)*log2(e)

    auto stage = [&](int mt, int bi){
        const size_t kb = kBase + (size_t)mt*32768;
        #pragma unroll
        for (int i=0;i<4;i++){
            const int row = i*8 + w;
            const int colb = (l*16) ^ ((row&7)<<4);
            __builtin_amdgcn_global_load_lds(
                AS1((const char*)kTh + kb + (size_t)row*1024 + colb),
                AS3((char*)khb[bi] + row*1024 + l*16), 16, 0, 0);
        }
    };

    auto qk_tile = [&](int kt, int par){
        // K-lo preload from global (L2-resident), R4-equivalent fragment data
        bf16x8 kflv[8];
        const size_t klrow = ((size_t)b*N_ + (size_t)kt*32 + fn*16 + lr)*C_ + ch*256 + lg*8;
        #pragma unroll
        for (int kc=0;kc<8;kc++) kflv[kc] = *(const bf16x8*)(kTl + klrow + kc*32);
        f32x4 s0 = (f32x4){0.f,0.f,0.f,0.f}, s1 = s0;
        const char* khB = (const char*)khb[kt&1];
        const int rbase = (fn*16 + lr)*1024;
        const int swz = ((fn*16+lr)&7)<<4;
        #pragma unroll
        for (int kc=0;kc<8;kc++){
            bf16x8 kf = *(const bf16x8*)(khB + rbase + ((ch*512 + kc*64 + lg*16) ^ swz));
            s0 = mfma16(qh[0][kc], kf,       s0);
            s0 = mfma16(ql[0][kc], kf,       s0);
            s0 = mfma16(qh[0][kc], kflv[kc], s0);
            s1 = mfma16(qh[1][kc], kf,       s1);
            s1 = mfma16(ql[1][kc], kf,       s1);
            s1 = mfma16(qh[1][kc], kflv[kc], s1);
        }
        #pragma unroll
        for (int r=0;r<4;r++){
            Sb[par][ch][fm2*32 +      lg*4 + r][fn*16 + lr] = s0[r]*SC2;
            Sb[par][ch][fm2*32 + 16 + lg*4 + r][fn*16 + lr] = s1[r]*SC2;
        }
    };

    auto softmax_pv = [&](int tt){
        const int par = tt&1;
        const int nrow = nh*32 + l31;
        // V prefetch: A-frags (c = cq*128+cb*32+l31, m contiguous 8)
        bf16x8 vfa[8];
        const size_t vrow = ((size_t)b*C_ + cq*128 + l31)*N_ + (size_t)tt*32 + h*8;
        #pragma unroll
        for (int cb=0;cb<4;cb++){
            vfa[cb*2+0] = *(const bf16x8*)(vB + vrow + (size_t)cb*32*N_);
            vfa[cb*2+1] = *(const bf16x8*)(vB + vrow + (size_t)cb*32*N_ + 16);
        }
        const float* r0 = &Sb[par][0][nrow][0];
        const float* r1 = &Sb[par][1][nrow][0];
        f32x4 a0 = *(const f32x4*)(r0 + h*8)     + *(const f32x4*)(r1 + h*8);
        f32x4 a1 = *(const f32x4*)(r0 + h*8 + 4) + *(const f32x4*)(r1 + h*8 + 4);
        f32x4 a2 = *(const f32x4*)(r0 + 16 + h*8)     + *(const f32x4*)(r1 + 16 + h*8);
        f32x4 a3 = *(const f32x4*)(r0 + 16 + h*8 + 4) + *(const f32x4*)(r1 + 16 + h*8 + 4);
        float mx;
        {
            f32x4 m01, m23;
            #pragma unroll
            for (int i=0;i<4;i++){ m01[i] = fmaxf(a0[i], a1[i]); m23[i] = fmaxf(a2[i], a3[i]); }
            float m0 = fmaxf(fmaxf(m01[0],m01[1]), fmaxf(m01[2],m01[3]));
            float m1 = fmaxf(fmaxf(m23[0],m23[1]), fmaxf(m23[2],m23[3]));
            mx = fmaxf(m0, m1);
        }
        mx = fmaxf(mx, __shfl_xor(mx, 32));
        const float mnew = fmaxf(m_run, mx);
        const float fsc = exp2f(m_run - mnew);
        m_run = mnew;
        float p[16];
        #pragma unroll
        for (int i=0;i<4;i++){
            p[i]    = exp2f(a0[i]-mnew);
            p[4+i]  = exp2f(a1[i]-mnew);
            p[8+i]  = exp2f(a2[i]-mnew);
            p[12+i] = exp2f(a3[i]-mnew);
        }
        float ps = ((p[0]+p[1])+(p[2]+p[3])) + ((p[4]+p[5])+(p[6]+p[7]))
                 + ((p[8]+p[9])+(p[10]+p[11])) + ((p[12]+p[13])+(p[14]+p[15]));
        ps += __shfl_xor(ps, 32);
        s_run = s_run*fsc + ps;
        bf16x8 pa0, pa1;
        #pragma unroll
        for (int j=0;j<8;j++){ pa0[j] = (__bf16)p[j]; pa1[j] = (__bf16)p[8+j]; }
        if (__any(fsc != 1.0f)){
            #pragma unroll
            for (int cb=0;cb<4;cb++) accO[cb] *= fsc;
        }
        #pragma unroll
        for (int cb=0;cb<4;cb++){
            accO[cb] = mfma32(vfa[cb*2+0], pa0, accO[cb]);
            accO[cb] = mfma32(vfa[cb*2+1], pa1, accO[cb]);
        }
    };

    // ---------------- prologue ----------------
    stage(0, 0);
    stage(1, 1);
    asm volatile("s_waitcnt vmcnt(0)" ::: "memory");
    __builtin_amdgcn_s_barrier();
    qk_tile(0, 0);
    asm volatile("s_waitcnt lgkmcnt(0)" ::: "memory");
    __builtin_amdgcn_s_barrier();

    // ---------------- main loop: one barrier per tile ----------------
    for (int tt=0; tt<128; ++tt){
        if (tt < 126) stage(tt+2, tt&1);
        if (tt < 127) qk_tile(tt+1, (tt+1)&1);
        softmax_pv(tt);
        asm volatile("s_waitcnt vmcnt(0) lgkmcnt(0)" ::: "memory");
        __builtin_amdgcn_s_barrier();
    }

    // ---------------- epilogue: normalize (per-lane) + write O^T ----------------
    {
        const float inv = 1.0f / s_run;
        const size_t orow = ((size_t)b*N_ + n0 + nh*32 + l31)*C_ + cq*128;
        #pragma unroll
        for (int cb=0;cb<4;cb++)
            #pragma unroll
            for (int g=0;g<4;g++){
                ushort4 o;
                o.x = f2bf(accO[cb][g*4+0]*inv);
                o.y = f2bf(accO[cb][g*4+1]*inv);
                o.z = f2bf(accO[cb][g*4+2]*inv);
                o.w = f2bf(accO[cb][g*4+3]*inv);
                *(ushort4*)(aoT + orow + cb*32 + g*8 + h*4) = o;
            }
    }
}

extern "C" void kernel_launch(void* const* d_in, const int* in_sizes, int n_in,
                              void* d_out, int out_size, void* d_ws, size_t ws_size,
                              hipStream_t stream)
{
    const float* x   = (const float*)d_in[0];
    const float* gnw = (const float*)d_in[1];
    const float* gnb = (const float*)d_in[2];
    const float* wq  = (const float*)d_in[3];
    const float* bq  = (const float*)d_in[4];
    const float* wk  = (const float*)d_in[5];
    const float* bk  = (const float*)d_in[6];
    const float* wv  = (const float*)d_in[7];
    const float* bv  = (const float*)d_in[8];
    const float* wp  = (const float*)d_in[9];
    const float* bp  = (const float*)d_in[10];
    float* out = (float*)d_out;

    char* ws = (char*)d_ws;
    size_t off = 0;
    auto alloc = [&](size_t bytes)->char*{
        char* p = ws + off; off += (bytes + 255) & ~(size_t)255; return p;
    };
    const size_t WB = (size_t)C_*C_*2;
    const size_t TB = (size_t)B_*N_*C_*2;
    unsigned short* wqh = (unsigned short*)alloc(WB);
    unsigned short* wql = (unsigned short*)alloc(WB);
    unsigned short* wkh = (unsigned short*)alloc(WB);
    unsigned short* wkl = (unsigned short*)alloc(WB);
    unsigned short* wvh = (unsigned short*)alloc(WB);
    unsigned short* wvl = (unsigned short*)alloc(WB);
    unsigned short* wph = (unsigned short*)alloc(WB);
    unsigned short* wpl = (unsigned short*)alloc(WB);
    unsigned short* hTh = (unsigned short*)alloc(TB);
    unsigned short* hTl = (unsigned short*)alloc(TB);
    unsigned short* qTh = (unsigned short*)alloc(TB);
    unsigned short* qTl = (unsigned short*)alloc(TB);
    unsigned short* kTh = (unsigned short*)alloc(TB);
    unsigned short* kTl = (unsigned short*)alloc(TB);
    unsigned short* vb  = (unsigned short*)alloc(TB);
    unsigned short* ao  = (unsigned short*)alloc(TB);
    float2* part  = (float2*)alloc(8*64*sizeof(float2));
    float2* stats = (float2*)alloc(8*sizeof(float2));

    split_w<<<256, 256, 0, stream>>>(wq, wqh, wql);
    split_w<<<256, 256, 0, stream>>>(wk, wkh, wkl);
    split_w<<<256, 256, 0, stream>>>(wv, wvh, wvl);
    split_w<<<256, 256, 0, stream>>>(wp, wph, wpl);
    gn_part<<<dim3(64, 8), 256, 0, stream>>>(x, part);
    gn_fin<<<8, 64, 0, stream>>>(part, stats);
    gn_apply<<<dim3(128, 16, B_), 256, 0, stream>>>(x, gnw, gnb, stats, hTh, hTl);
    conv_gemm<3,0><<<dim3(32,4,B_), 256, 0, stream>>>(wqh,wql,hTh,hTl,bq, qTh,qTl,nullptr,nullptr);
    conv_gemm<3,0><<<dim3(32,4,B_), 256, 0, stream>>>(wkh,wkl,hTh,hTl,bk, kTh,kTl,nullptr,nullptr);
    conv_gemm<1,1><<<dim3(32,4,B_), 256, 0, stream>>>(wvh,wvl,hTh,hTl,bv, vb,nullptr,nullptr,nullptr);
    attn_flash9<<<dim3(256), 512, 0, stream>>>(qTh,qTl,kTh,kTl,vb,ao);
    conv_gemm<1,2><<<dim3(32,4,B_), 256, 0, stream>>>(wph,wpl,ao,nullptr,bp, nullptr,nullptr,out,x);
}

// Round 11
// 738.041 us; speedup vs baseline: 1.4623x; 1.1428x over previous
//
#include <hip/hip_runtime.h>
#include <hip/hip_bf16.h>
#include <math.h>

#define B_ 4
#define C_ 512
#define N_ 4096

typedef float f32x4 __attribute__((ext_vector_type(4)));
typedef __bf16 bf16x8 __attribute__((ext_vector_type(8)));

#define AS1(p) ((const __attribute__((address_space(1))) unsigned int*)(p))
#define AS3(p) ((__attribute__((address_space(3))) unsigned int*)(p))

__device__ __forceinline__ unsigned short f2bf(float x){
    return __builtin_bit_cast(unsigned short, (__bf16)x);
}
__device__ __forceinline__ float bf2f(unsigned short b){
    unsigned u = ((unsigned)b)<<16;
    return __builtin_bit_cast(float, u);
}
__device__ __forceinline__ f32x4 mfma16(bf16x8 a, bf16x8 b, f32x4 c){
    return __builtin_amdgcn_mfma_f32_16x16x32_bf16(a, b, c, 0, 0, 0);
}

// ---------------- weight fp32 -> bf16 hi/lo split ----------------
__global__ void split_w(const float* __restrict__ src, unsigned short* __restrict__ hi,
                        unsigned short* __restrict__ lo){
    const int i = (blockIdx.x*256 + threadIdx.x)*4;
    f32x4 v = *(const f32x4*)(src + i);
    ushort4 h, l;
    unsigned short t0=f2bf(v[0]); h.x=t0; l.x=f2bf(v[0]-bf2f(t0));
    unsigned short t1=f2bf(v[1]); h.y=t1; l.y=f2bf(v[1]-bf2f(t1));
    unsigned short t2=f2bf(v[2]); h.z=t2; l.z=f2bf(v[2]-bf2f(t2));
    unsigned short t3=f2bf(v[3]); h.w=t3; l.w=f2bf(v[3]-bf2f(t3));
    *(ushort4*)(hi + i) = h;
    *(ushort4*)(lo + i) = l;
}

// ---------------- GroupNorm: partial sums ----------------
__global__ void gn_part(const float* __restrict__ x, float2* __restrict__ part){
    const int bg = blockIdx.y, blk = blockIdx.x, t = threadIdx.x;
    const float* base = x + (size_t)bg*(256*4096) + (size_t)blk*16384;
    float s = 0.f, q = 0.f;
    for (int i=0;i<16;i++){
        f32x4 v = *(const f32x4*)(base + i*1024 + t*4);
        s += v[0]+v[1]+v[2]+v[3];
        q += v[0]*v[0]+v[1]*v[1]+v[2]*v[2]+v[3]*v[3];
    }
    #pragma unroll
    for (int o=32;o>0;o>>=1){ s += __shfl_down(s, o); q += __shfl_down(q, o); }
    __shared__ float as[4], aq[4];
    if ((t&63)==0){ as[t>>6]=s; aq[t>>6]=q; }
    __syncthreads();
    if (t==0)
        part[bg*64 + blk] = make_float2(as[0]+as[1]+as[2]+as[3], aq[0]+aq[1]+aq[2]+aq[3]);
}

__global__ void gn_fin(const float2* __restrict__ part, float2* __restrict__ stats){
    const int bg = blockIdx.x, t = threadIdx.x;
    float2 p = part[bg*64 + t];
    float s = p.x, q = p.y;
    #pragma unroll
    for (int o=32;o>0;o>>=1){ s += __shfl_down(s,o); q += __shfl_down(q,o); }
    if (t==0){
        const float inv = 1.0f/(256.f*4096.f);
        float mu = s*inv;
        float var = q*inv - mu*mu;
        stats[bg] = make_float2(mu, rsqrtf(var + 1e-6f));
    }
}

// ---- GN apply + transpose + hi/lo split: x[B][C][N] -> hT[B][N][C] (bf16 hi,lo) ----
__global__ void gn_apply(const float* __restrict__ x, const float* __restrict__ gw,
                         const float* __restrict__ gb, const float2* __restrict__ stats,
                         unsigned short* __restrict__ hTh, unsigned short* __restrict__ hTl)
{
    const int b = blockIdx.z, c0 = blockIdx.y*32, n0 = blockIdx.x*32;
    const int t = threadIdx.x;
    __shared__ float tile[32][37];
    {
        const int cl = t>>3, nl = (t&7)*4;
        const int c = c0 + cl;
        const float2 st = stats[b*2 + (c>>8)];
        const float wv = gw[c], bvv = gb[c];
        const f32x4 v = *(const f32x4*)(x + ((size_t)b*C_ + c)*N_ + n0 + nl);
        #pragma unroll
        for (int i=0;i<4;i++) tile[cl][nl+i] = (v[i] - st.x)*st.y*wv + bvv;
    }
    __syncthreads();
    {
        const int nl = t>>3, cl = (t&7)*4;
        const int n = n0 + nl;
        float f0 = tile[cl+0][nl], f1 = tile[cl+1][nl], f2 = tile[cl+2][nl], f3 = tile[cl+3][nl];
        unsigned short h0=f2bf(f0), h1=f2bf(f1), h2=f2bf(f2), h3=f2bf(f3);
        ushort4 hh, ll;
        hh.x=h0; hh.y=h1; hh.z=h2; hh.w=h3;
        ll.x=f2bf(f0-bf2f(h0)); ll.y=f2bf(f1-bf2f(h1));
        ll.z=f2bf(f2-bf2f(h2)); ll.w=f2bf(f3-bf2f(h3));
        size_t o = ((size_t)b*N_ + n)*C_ + c0 + cl;
        *(ushort4*)(hTh + o) = hh;
        *(ushort4*)(hTl + o) = ll;
    }
}

// ---------------- conv GEMM: out[o,n] = sum_c W[o,c]*S[c,n] + bias[o] ----------------
template<int PROD, int MODE>
__global__ __launch_bounds__(256, 2) void conv_gemm(
    const unsigned short* __restrict__ Wh, const unsigned short* __restrict__ Wl,
    const unsigned short* __restrict__ Sh, const unsigned short* __restrict__ Sl,
    const float* __restrict__ bias,
    unsigned short* __restrict__ outHi, unsigned short* __restrict__ outLo,
    float* __restrict__ outF, const float* __restrict__ resid)
{
    const int b = blockIdx.z, o0 = blockIdx.y*128, n0 = blockIdx.x*128;
    const int t = threadIdx.x, w = t>>6, l = t&63, lr = l&15, lg = l>>4;
    const int ro = (w>>1)*64, co = (w&1)*64;
    __shared__ unsigned short Ah[128][40];
    __shared__ unsigned short Al[128][40];
    __shared__ unsigned short Bh[128][40];
    __shared__ unsigned short Bl[128][40];
    f32x4 acc[4][4];
    #pragma unroll
    for (int i=0;i<4;i++)
        #pragma unroll
        for (int j=0;j<4;j++) acc[i][j] = (f32x4){0.f,0.f,0.f,0.f};

    const size_t srcB = (size_t)b*N_*C_;
    for (int ks=0; ks<16; ks++){
        const int c0 = ks*32;
        #pragma unroll
        for (int i=0;i<2;i++){
            int u = t + i*256;
            int row = u>>2, sch = (u&3)*8;
            *(bf16x8*)&Ah[row][sch] = *(const bf16x8*)(Wh + (size_t)(o0+row)*C_ + c0 + sch);
            *(bf16x8*)&Bh[row][sch] = *(const bf16x8*)(Sh + srcB + (size_t)(n0+row)*C_ + c0 + sch);
            if constexpr (PROD==3){
                *(bf16x8*)&Al[row][sch] = *(const bf16x8*)(Wl + (size_t)(o0+row)*C_ + c0 + sch);
                *(bf16x8*)&Bl[row][sch] = *(const bf16x8*)(Sl + srcB + (size_t)(n0+row)*C_ + c0 + sch);
            }
        }
        __syncthreads();
        bf16x8 af[4], bfv[4], afl[4], bfl[4];
        #pragma unroll
        for (int i=0;i<4;i++){
            af[i]  = *(const bf16x8*)&Ah[ro + i*16 + lr][lg*8];
            bfv[i] = *(const bf16x8*)&Bh[co + i*16 + lr][lg*8];
            if constexpr (PROD==3){
                afl[i] = *(const bf16x8*)&Al[ro + i*16 + lr][lg*8];
                bfl[i] = *(const bf16x8*)&Bl[co + i*16 + lr][lg*8];
            }
        }
        #pragma unroll
        for (int i=0;i<4;i++)
            #pragma unroll
            for (int j=0;j<4;j++){
                acc[i][j] = mfma16(af[i], bfv[j], acc[i][j]);
                if constexpr (PROD==3){
                    acc[i][j] = mfma16(af[i],  bfl[j], acc[i][j]);
                    acc[i][j] = mfma16(afl[i], bfv[j], acc[i][j]);
                }
            }
        __syncthreads();
    }
    #pragma unroll
    for (int i=0;i<4;i++){
        const int ob = o0 + ro + i*16 + lg*4;
        #pragma unroll
        for (int j=0;j<4;j++){
            const int n = n0 + co + j*16 + lr;
            f32x4 v = acc[i][j];
            if constexpr (MODE==0){
                float v0 = v[0] + bias[ob+0]; unsigned short h0 = f2bf(v0);
                float v1 = v[1] + bias[ob+1]; unsigned short h1 = f2bf(v1);
                float v2 = v[2] + bias[ob+2]; unsigned short h2 = f2bf(v2);
                float v3 = v[3] + bias[ob+3]; unsigned short h3 = f2bf(v3);
                ushort4 hh, ll;
                hh.x=h0; hh.y=h1; hh.z=h2; hh.w=h3;
                ll.x=f2bf(v0-bf2f(h0)); ll.y=f2bf(v1-bf2f(h1));
                ll.z=f2bf(v2-bf2f(h2)); ll.w=f2bf(v3-bf2f(h3));
                *(ushort4*)(outHi + srcB + (size_t)n*C_ + ob) = hh;
                *(ushort4*)(outLo + srcB + (size_t)n*C_ + ob) = ll;
            } else if constexpr (MODE==1){
                #pragma unroll
                for (int r=0;r<4;r++)
                    outHi[((size_t)b*C_ + ob + r)*N_ + n] = f2bf(v[r] + bias[ob+r]);
            } else {
                #pragma unroll
                for (int r=0;r<4;r++){
                    size_t idx = ((size_t)b*C_ + ob + r)*N_ + n;
                    outF[idx] = resid[idx] + v[r] + bias[ob+r];
                }
            }
        }
    }
}

// ------ flash attention v11: R10 with LDS buffer-stride bug fixed ------
// 512 blocks x 256 threads (4 waves). 32 q-rows/block, KVBLK=16, K hi+lo dbuf
// in LDS (16384 B per tile per array), total LDS ~70 KB -> 2 blocks/CU with
// independent barriers: while block A is in softmax/barrier, block B's QK
// MFMAs issue on the same SIMD. QK waves: (fm, ch); PV: wave owns c-block w*128.
// PV uses K=32 mfma with upper half of P zeroed (lanes lg>=2).
__global__ __launch_bounds__(256, 2) void attn_flash11(
    const unsigned short* __restrict__ qTh, const unsigned short* __restrict__ qTl,
    const unsigned short* __restrict__ kTh, const unsigned short* __restrict__ kTl,
    const unsigned short* __restrict__ vB,  unsigned short* __restrict__ aoT)
{
    const int id = blockIdx.x;
    const int xcd = id & 7, slot = id >> 3;          // 64 slots per XCD
    const int b = xcd >> 1;                          // 2 XCDs per batch
    const int n0 = ((xcd & 1)*64 + slot)*32;
    const int t = threadIdx.x, w = t>>6, l = t&63, lr = l&15, lg = l>>4;
    const int fm = w>>1, ch = w&1;                   // QK role
    const int cw = w*128;                            // PV role: c-block

    __shared__ unsigned short khb[2][16*512];        // K-hi dbuf: 16384 B per buffer
    __shared__ unsigned short klb[2][16*512];        // K-lo dbuf
    __shared__ float Sb[2][32][18];                  // [ch][n][m], stride 18 (2-way free)
    __shared__ __align__(16) unsigned short Pb[32][24];
    __shared__ float rowM[32], rowS[32], rowF[32];

    // q fragments: rows n0 + fm*16 + lr, c-half ch, hi+lo (64 VGPR)
    bf16x8 qh[8], ql[8];
    {
        const size_t qr = ((size_t)b*N_ + n0 + fm*16 + lr)*C_ + ch*256;
        #pragma unroll
        for (int kc=0; kc<8; kc++){
            qh[kc] = *(const bf16x8*)(qTh + qr + kc*32 + lg*8);
            ql[kc] = *(const bf16x8*)(qTl + qr + kc*32 + lg*8);
        }
    }
    f32x4 accO[2][8];                                // 32 rows x 128 c per wave
    #pragma unroll
    for (int i=0;i<2;i++)
        #pragma unroll
        for (int j=0;j<8;j++) accO[i][j] = (f32x4){0.f,0.f,0.f,0.f};
    if (t < 32){ rowM[t] = -INFINITY; rowS[t] = 0.f; }

    const size_t kBase = (size_t)b*N_*1024;          // bytes; C_*2 per row
    const float SC2 = 32.6444622284f;                // sqrt(512)*log2(e)

    auto stage = [&](int mt, int bi){
        const size_t kb = kBase + (size_t)mt*16*1024;
        #pragma unroll
        for (int i=0;i<4;i++){
            const int row = i*4 + w;                 // 16 rows, 4 waves
            const int colb = (l*16) ^ ((row&7)<<4);
            const size_t g = kb + (size_t)row*1024 + colb;
            const int d = bi*16384 + row*1024 + l*16;   // FIXED: 16384-B buffer stride
            __builtin_amdgcn_global_load_lds(AS1((const char*)kTh + g), AS3((char*)khb + d), 16, 0, 0);
            __builtin_amdgcn_global_load_lds(AS1((const char*)kTl + g), AS3((char*)klb + d), 16, 0, 0);
        }
    };

    auto qk_tile = [&](int kt){
        const char* kh = (const char*)khb + (kt&1)*16384;   // FIXED stride
        const char* kl = (const char*)klb + (kt&1)*16384;
        f32x4 s = (f32x4){0.f,0.f,0.f,0.f};
        const int rbase = lr*1024;                   // K row = m-col = lr
        const int swz = (lr&7)<<4;
        __builtin_amdgcn_s_setprio(1);
        #pragma unroll
        for (int kc=0;kc<8;kc++){
            const int o = rbase + ((ch*512 + kc*64 + lg*16) ^ swz);
            bf16x8 kf  = *(const bf16x8*)(kh + o);
            bf16x8 kfl = *(const bf16x8*)(kl + o);
            s = mfma16(qh[kc], kf,  s);
            s = mfma16(ql[kc], kf,  s);
            s = mfma16(qh[kc], kfl, s);
        }
        __builtin_amdgcn_s_setprio(0);
        #pragma unroll
        for (int r=0;r<4;r++)
            Sb[ch][fm*16 + lg*4 + r][lr] = s[r]*SC2;
    };

    // ---------------- prologue ----------------
    stage(0, 0);
    stage(1, 1);
    asm volatile("s_waitcnt vmcnt(0)" ::: "memory");
    __builtin_amdgcn_s_barrier();
    qk_tile(0);
    asm volatile("s_waitcnt lgkmcnt(0)" ::: "memory");
    __builtin_amdgcn_s_barrier();

    for (int tt=0; tt<256; ++tt){
        // ---- phase1: online softmax (exp2 domain), 8 threads/row x 2 cols ----
        {
            const int row = t>>3, j = t&7;
            float a0 = Sb[0][row][j*2+0] + Sb[1][row][j*2+0];
            float a1 = Sb[0][row][j*2+1] + Sb[1][row][j*2+1];
            float mx = fmaxf(a0, a1);
            mx = fmaxf(mx, __shfl_xor(mx, 1, 8));
            mx = fmaxf(mx, __shfl_xor(mx, 2, 8));
            mx = fmaxf(mx, __shfl_xor(mx, 4, 8));
            const float mprev = rowM[row];
            const float mnew = fmaxf(mprev, mx);
            float p0 = exp2f(a0 - mnew), p1 = exp2f(a1 - mnew);
            float ps = p0 + p1;
            ps += __shfl_xor(ps, 1, 8);
            ps += __shfl_xor(ps, 2, 8);
            ps += __shfl_xor(ps, 4, 8);
            ushort2 pk; pk.x = f2bf(p0); pk.y = f2bf(p1);
            *(ushort2*)&Pb[row][j*2] = pk;
            if (j==0){
                float f = exp2f(mprev - mnew);
                rowF[row] = f;
                rowS[row] = rowS[row]*f + ps;
                rowM[row] = mnew;
            }
        }
        asm volatile("s_waitcnt vmcnt(0) lgkmcnt(0)" ::: "memory");
        __builtin_amdgcn_s_barrier();

        // ---- phase2: stage(t+2) | loadV(t) | PV(t) | QK(t+1) ----
        if (tt < 254) stage(tt+2, tt&1);
        {
            // V fragments (B-operand, K=32 with duplicated upper half)
            bf16x8 vf[8];
            const size_t vcol = (size_t)tt*16 + (lg&1)*8;
            #pragma unroll
            for (int cf=0;cf<8;cf++)
                vf[cf] = *(const bf16x8*)(vB + ((size_t)b*C_ + cw + cf*16 + lr)*N_ + vcol);
            // rescale (gated)
            float frv[2][4]; bool need = false;
            #pragma unroll
            for (int am=0;am<2;am++)
                #pragma unroll
                for (int r=0;r<4;r++){
                    frv[am][r] = rowF[am*16 + lg*4 + r];
                    need |= (frv[am][r] != 1.0f);
                }
            if (__any(need)){
                #pragma unroll
                for (int am=0;am<2;am++)
                    #pragma unroll
                    for (int cf=0;cf<8;cf++)
                        #pragma unroll
                        for (int r=0;r<4;r++) accO[am][cf][r] *= frv[am][r];
            }
            // P fragments: upper K half zeroed (lanes lg>=2)
            bf16x8 pa[2];
            #pragma unroll
            for (int am=0;am<2;am++){
                if (lg < 2) pa[am] = *(const bf16x8*)&Pb[am*16 + lr][lg*8];
                else        pa[am] = __builtin_bit_cast(bf16x8, (f32x4){0.f,0.f,0.f,0.f});
            }
            __builtin_amdgcn_s_setprio(1);
            #pragma unroll
            for (int cf=0;cf<8;cf++)
                #pragma unroll
                for (int am=0;am<2;am++)
                    accO[am][cf] = mfma16(pa[am], vf[cf], accO[am][cf]);
            __builtin_amdgcn_s_setprio(0);
        }
        if (tt < 255) qk_tile(tt+1);
        asm volatile("s_waitcnt lgkmcnt(0)" ::: "memory");
        __builtin_amdgcn_s_barrier();
    }

    // ---- normalize + write aoT[B][N][C] ----
    #pragma unroll
    for (int am=0;am<2;am++)
        #pragma unroll
        for (int r=0;r<4;r++){
            const int n = am*16 + lg*4 + r;
            const float inv = 1.0f / rowS[n];
            #pragma unroll
            for (int cf=0;cf<8;cf++)
                aoT[((size_t)b*N_ + n0 + n)*C_ + cw + cf*16 + lr] = f2bf(accO[am][cf][r]*inv);
        }
}

extern "C" void kernel_launch(void* const* d_in, const int* in_sizes, int n_in,
                              void* d_out, int out_size, void* d_ws, size_t ws_size,
                              hipStream_t stream)
{
    const float* x   = (const float*)d_in[0];
    const float* gnw = (const float*)d_in[1];
    const float* gnb = (const float*)d_in[2];
    const float* wq  = (const float*)d_in[3];
    const float* bq  = (const float*)d_in[4];
    const float* wk  = (const float*)d_in[5];
    const float* bk  = (const float*)d_in[6];
    const float* wv  = (const float*)d_in[7];
    const float* bv  = (const float*)d_in[8];
    const float* wp  = (const float*)d_in[9];
    const float* bp  = (const float*)d_in[10];
    float* out = (float*)d_out;

    char* ws = (char*)d_ws;
    size_t off = 0;
    auto alloc = [&](size_t bytes)->char*{
        char* p = ws + off; off += (bytes + 255) & ~(size_t)255; return p;
    };
    const size_t WB = (size_t)C_*C_*2;
    const size_t TB = (size_t)B_*N_*C_*2;
    unsigned short* wqh = (unsigned short*)alloc(WB);
    unsigned short* wql = (unsigned short*)alloc(WB);
    unsigned short* wkh = (unsigned short*)alloc(WB);
    unsigned short* wkl = (unsigned short*)alloc(WB);
    unsigned short* wvh = (unsigned short*)alloc(WB);
    unsigned short* wvl = (unsigned short*)alloc(WB);
    unsigned short* wph = (unsigned short*)alloc(WB);
    unsigned short* wpl = (unsigned short*)alloc(WB);
    unsigned short* hTh = (unsigned short*)alloc(TB);
    unsigned short* hTl = (unsigned short*)alloc(TB);
    unsigned short* qTh = (unsigned short*)alloc(TB);
    unsigned short* qTl = (unsigned short*)alloc(TB);
    unsigned short* kTh = (unsigned short*)alloc(TB);
    unsigned short* kTl = (unsigned short*)alloc(TB);
    unsigned short* vb  = (unsigned short*)alloc(TB);
    unsigned short* ao  = (unsigned short*)alloc(TB);
    float2* part  = (float2*)alloc(8*64*sizeof(float2));
    float2* stats = (float2*)alloc(8*sizeof(float2));

    split_w<<<256, 256, 0, stream>>>(wq, wqh, wql);
    split_w<<<256, 256, 0, stream>>>(wk, wkh, wkl);
    split_w<<<256, 256, 0, stream>>>(wv, wvh, wvl);
    split_w<<<256, 256, 0, stream>>>(wp, wph, wpl);
    gn_part<<<dim3(64, 8), 256, 0, stream>>>(x, part);
    gn_fin<<<8, 64, 0, stream>>>(part, stats);
    gn_apply<<<dim3(128, 16, B_), 256, 0, stream>>>(x, gnw, gnb, stats, hTh, hTl);
    conv_gemm<3,0><<<dim3(32,4,B_), 256, 0, stream>>>(wqh,wql,hTh,hTl,bq, qTh,qTl,nullptr,nullptr);
    conv_gemm<3,0><<<dim3(32,4,B_), 256, 0, stream>>>(wkh,wkl,hTh,hTl,bk, kTh,kTl,nullptr,nullptr);
    conv_gemm<1,1><<<dim3(32,4,B_), 256, 0, stream>>>(wvh,wvl,hTh,hTl,bv, vb,nullptr,nullptr,nullptr);
    attn_flash11<<<dim3(512), 256, 0, stream>>>(qTh,qTl,kTh,kTl,vb,ao);
    conv_gemm<1,2><<<dim3(32,4,B_), 256, 0, stream>>>(wph,wpl,ao,nullptr,bp, nullptr,nullptr,out,x);
}

// Round 12
// 544.065 us; speedup vs baseline: 1.9837x; 1.3565x over previous
//
#include <hip/hip_runtime.h>
#include <hip/hip_bf16.h>
#include <math.h>

#define B_ 4
#define C_ 512
#define N_ 4096

typedef float f32x4 __attribute__((ext_vector_type(4)));
typedef __bf16 bf16x8 __attribute__((ext_vector_type(8)));

#define AS1(p) ((const __attribute__((address_space(1))) unsigned int*)(p))
#define AS3(p) ((__attribute__((address_space(3))) unsigned int*)(p))

__device__ __forceinline__ unsigned short f2bf(float x){
    return __builtin_bit_cast(unsigned short, (__bf16)x);
}
__device__ __forceinline__ float bf2f(unsigned short b){
    unsigned u = ((unsigned)b)<<16;
    return __builtin_bit_cast(float, u);
}
__device__ __forceinline__ f32x4 mfma16(bf16x8 a, bf16x8 b, f32x4 c){
    return __builtin_amdgcn_mfma_f32_16x16x32_bf16(a, b, c, 0, 0, 0);
}

// ---------------- weight fp32 -> bf16 hi/lo split ----------------
__global__ void split_w(const float* __restrict__ src, unsigned short* __restrict__ hi,
                        unsigned short* __restrict__ lo){
    const int i = (blockIdx.x*256 + threadIdx.x)*4;
    f32x4 v = *(const f32x4*)(src + i);
    ushort4 h, l;
    unsigned short t0=f2bf(v[0]); h.x=t0; l.x=f2bf(v[0]-bf2f(t0));
    unsigned short t1=f2bf(v[1]); h.y=t1; l.y=f2bf(v[1]-bf2f(t1));
    unsigned short t2=f2bf(v[2]); h.z=t2; l.z=f2bf(v[2]-bf2f(t2));
    unsigned short t3=f2bf(v[3]); h.w=t3; l.w=f2bf(v[3]-bf2f(t3));
    *(ushort4*)(hi + i) = h;
    *(ushort4*)(lo + i) = l;
}

// ---------------- GroupNorm: partial sums ----------------
__global__ void gn_part(const float* __restrict__ x, float2* __restrict__ part){
    const int bg = blockIdx.y, blk = blockIdx.x, t = threadIdx.x;
    const float* base = x + (size_t)bg*(256*4096) + (size_t)blk*16384;
    float s = 0.f, q = 0.f;
    for (int i=0;i<16;i++){
        f32x4 v = *(const f32x4*)(base + i*1024 + t*4);
        s += v[0]+v[1]+v[2]+v[3];
        q += v[0]*v[0]+v[1]*v[1]+v[2]*v[2]+v[3]*v[3];
    }
    #pragma unroll
    for (int o=32;o>0;o>>=1){ s += __shfl_down(s, o); q += __shfl_down(q, o); }
    __shared__ float as[4], aq[4];
    if ((t&63)==0){ as[t>>6]=s; aq[t>>6]=q; }
    __syncthreads();
    if (t==0)
        part[bg*64 + blk] = make_float2(as[0]+as[1]+as[2]+as[3], aq[0]+aq[1]+aq[2]+aq[3]);
}

__global__ void gn_fin(const float2* __restrict__ part, float2* __restrict__ stats){
    const int bg = blockIdx.x, t = threadIdx.x;
    float2 p = part[bg*64 + t];
    float s = p.x, q = p.y;
    #pragma unroll
    for (int o=32;o>0;o>>=1){ s += __shfl_down(s,o); q += __shfl_down(q,o); }
    if (t==0){
        const float inv = 1.0f/(256.f*4096.f);
        float mu = s*inv;
        float var = q*inv - mu*mu;
        stats[bg] = make_float2(mu, rsqrtf(var + 1e-6f));
    }
}

// ---- GN apply + transpose + hi/lo split: x[B][C][N] -> hT[B][N][C] (bf16 hi,lo) ----
__global__ void gn_apply(const float* __restrict__ x, const float* __restrict__ gw,
                         const float* __restrict__ gb, const float2* __restrict__ stats,
                         unsigned short* __restrict__ hTh, unsigned short* __restrict__ hTl)
{
    const int b = blockIdx.z, c0 = blockIdx.y*32, n0 = blockIdx.x*32;
    const int t = threadIdx.x;
    __shared__ float tile[32][37];
    {
        const int cl = t>>3, nl = (t&7)*4;
        const int c = c0 + cl;
        const float2 st = stats[b*2 + (c>>8)];
        const float wv = gw[c], bvv = gb[c];
        const f32x4 v = *(const f32x4*)(x + ((size_t)b*C_ + c)*N_ + n0 + nl);
        #pragma unroll
        for (int i=0;i<4;i++) tile[cl][nl+i] = (v[i] - st.x)*st.y*wv + bvv;
    }
    __syncthreads();
    {
        const int nl = t>>3, cl = (t&7)*4;
        const int n = n0 + nl;
        float f0 = tile[cl+0][nl], f1 = tile[cl+1][nl], f2 = tile[cl+2][nl], f3 = tile[cl+3][nl];
        unsigned short h0=f2bf(f0), h1=f2bf(f1), h2=f2bf(f2), h3=f2bf(f3);
        ushort4 hh, ll;
        hh.x=h0; hh.y=h1; hh.z=h2; hh.w=h3;
        ll.x=f2bf(f0-bf2f(h0)); ll.y=f2bf(f1-bf2f(h1));
        ll.z=f2bf(f2-bf2f(h2)); ll.w=f2bf(f3-bf2f(h3));
        size_t o = ((size_t)b*N_ + n)*C_ + c0 + cl;
        *(ushort4*)(hTh + o) = hh;
        *(ushort4*)(hTl + o) = ll;
    }
}

// ---------------- conv GEMM: out[o,n] = sum_c W[o,c]*S[c,n] + bias[o] ----------------
template<int PROD, int MODE>
__global__ __launch_bounds__(256, 2) void conv_gemm(
    const unsigned short* __restrict__ Wh, const unsigned short* __restrict__ Wl,
    const unsigned short* __restrict__ Sh, const unsigned short* __restrict__ Sl,
    const float* __restrict__ bias,
    unsigned short* __restrict__ outHi, unsigned short* __restrict__ outLo,
    float* __restrict__ outF, const float* __restrict__ resid)
{
    const int b = blockIdx.z, o0 = blockIdx.y*128, n0 = blockIdx.x*128;
    const int t = threadIdx.x, w = t>>6, l = t&63, lr = l&15, lg = l>>4;
    const int ro = (w>>1)*64, co = (w&1)*64;
    __shared__ unsigned short Ah[128][40];
    __shared__ unsigned short Al[128][40];
    __shared__ unsigned short Bh[128][40];
    __shared__ unsigned short Bl[128][40];
    f32x4 acc[4][4];
    #pragma unroll
    for (int i=0;i<4;i++)
        #pragma unroll
        for (int j=0;j<4;j++) acc[i][j] = (f32x4){0.f,0.f,0.f,0.f};

    const size_t srcB = (size_t)b*N_*C_;
    for (int ks=0; ks<16; ks++){
        const int c0 = ks*32;
        #pragma unroll
        for (int i=0;i<2;i++){
            int u = t + i*256;
            int row = u>>2, sch = (u&3)*8;
            *(bf16x8*)&Ah[row][sch] = *(const bf16x8*)(Wh + (size_t)(o0+row)*C_ + c0 + sch);
            *(bf16x8*)&Bh[row][sch] = *(const bf16x8*)(Sh + srcB + (size_t)(n0+row)*C_ + c0 + sch);
            if constexpr (PROD==3){
                *(bf16x8*)&Al[row][sch] = *(const bf16x8*)(Wl + (size_t)(o0+row)*C_ + c0 + sch);
                *(bf16x8*)&Bl[row][sch] = *(const bf16x8*)(Sl + srcB + (size_t)(n0+row)*C_ + c0 + sch);
            }
        }
        __syncthreads();
        bf16x8 af[4], bfv[4], afl[4], bfl[4];
        #pragma unroll
        for (int i=0;i<4;i++){
            af[i]  = *(const bf16x8*)&Ah[ro + i*16 + lr][lg*8];
            bfv[i] = *(const bf16x8*)&Bh[co + i*16 + lr][lg*8];
            if constexpr (PROD==3){
                afl[i] = *(const bf16x8*)&Al[ro + i*16 + lr][lg*8];
                bfl[i] = *(const bf16x8*)&Bl[co + i*16 + lr][lg*8];
            }
        }
        #pragma unroll
        for (int i=0;i<4;i++)
            #pragma unroll
            for (int j=0;j<4;j++){
                acc[i][j] = mfma16(af[i], bfv[j], acc[i][j]);
                if constexpr (PROD==3){
                    acc[i][j] = mfma16(af[i],  bfl[j], acc[i][j]);
                    acc[i][j] = mfma16(afl[i], bfv[j], acc[i][j]);
                }
            }
        __syncthreads();
    }
    #pragma unroll
    for (int i=0;i<4;i++){
        const int ob = o0 + ro + i*16 + lg*4;
        #pragma unroll
        for (int j=0;j<4;j++){
            const int n = n0 + co + j*16 + lr;
            f32x4 v = acc[i][j];
            if constexpr (MODE==0){
                float v0 = v[0] + bias[ob+0]; unsigned short h0 = f2bf(v0);
                float v1 = v[1] + bias[ob+1]; unsigned short h1 = f2bf(v1);
                float v2 = v[2] + bias[ob+2]; unsigned short h2 = f2bf(v2);
                float v3 = v[3] + bias[ob+3]; unsigned short h3 = f2bf(v3);
                ushort4 hh, ll;
                hh.x=h0; hh.y=h1; hh.z=h2; hh.w=h3;
                ll.x=f2bf(v0-bf2f(h0)); ll.y=f2bf(v1-bf2f(h1));
                ll.z=f2bf(v2-bf2f(h2)); ll.w=f2bf(v3-bf2f(h3));
                *(ushort4*)(outHi + srcB + (size_t)n*C_ + ob) = hh;
                *(ushort4*)(outLo + srcB + (size_t)n*C_ + ob) = ll;
            } else if constexpr (MODE==1){
                #pragma unroll
                for (int r=0;r<4;r++)
                    outHi[((size_t)b*C_ + ob + r)*N_ + n] = f2bf(v[r] + bias[ob+r]);
            } else {
                #pragma unroll
                for (int r=0;r<4;r++){
                    size_t idx = ((size_t)b*C_ + ob + r)*N_ + n;
                    outF[idx] = resid[idx] + v[r] + bias[ob+r];
                }
            }
        }
    }
}

// -------- flash attention v12: R4 skeleton + stride-36 Sb + exp2 + counted vmcnt --------
// phase1(it): [stage K(it+2) DMA issued here] || softmax(it) [exp2 domain]
//             -> s_waitcnt vmcnt(8) lgkm(0); barrier   (drains K(it+1)+V(it), keeps K(it+2) in flight)
// phase2(it): PV(it) | loadV(it+1) | QK(it+1) -> lgkm(0) barrier
__global__ __launch_bounds__(512, 2) void attn_flash12(
    const unsigned short* __restrict__ qTh, const unsigned short* __restrict__ qTl,
    const unsigned short* __restrict__ kTh, const unsigned short* __restrict__ kTl,
    const unsigned short* __restrict__ vB,  unsigned short* __restrict__ aoT)
{
    const int id = blockIdx.x;
    const int xcd = id & 7, slot = id >> 3;
    const int b = xcd >> 1;
    const int n0 = ((xcd & 1)*32 + slot)*64;
    const int t = threadIdx.x, w = t>>6, l = t&63, lr = l&15, lg = l>>4;
    const int fm2 = w>>2, fn = (w>>1)&1, ch = w&1;
    const int cw = w*64;

    __shared__ unsigned short khA[32*512];
    __shared__ unsigned short klA[32*512];
    __shared__ unsigned short khB[32*512];
    __shared__ unsigned short klB[32*512];
    __shared__ __align__(16) float Sb[2][64][36];       // stride 36: 2-way-free writes, 16B-aligned reads
    __shared__ __align__(16) unsigned short Pb[64*32];  // rotated-slot layout (R4)
    __shared__ float rowM[64], rowS[64], rowF[64];

    // q fragments: 2 row-frags (fm2*32 + f*16), c-half ch, hi+lo
    bf16x8 qh[2][8], ql[2][8];
    #pragma unroll
    for (int f=0; f<2; f++){
        const size_t qr = ((size_t)b*N_ + n0 + fm2*32 + f*16 + lr)*C_ + ch*256;
        #pragma unroll
        for (int kc=0; kc<8; kc++){
            qh[f][kc] = *(const bf16x8*)(qTh + qr + kc*32 + lg*8);
            ql[f][kc] = *(const bf16x8*)(qTl + qr + kc*32 + lg*8);
        }
    }
    f32x4 accO[4][4];
    #pragma unroll
    for (int i=0;i<4;i++)
        #pragma unroll
        for (int j=0;j<4;j++) accO[i][j] = (f32x4){0.f,0.f,0.f,0.f};
    if (t < 64){ rowM[t] = -INFINITY; rowS[t] = 0.f; }

    const size_t kBase = (size_t)b*N_*1024;   // bytes; C_*2 per row

    auto stage = [&](int mt, unsigned short* dh, unsigned short* dl){
        const size_t kb = kBase + (size_t)mt*32*1024;
        #pragma unroll
        for (int i=0;i<4;i++){
            const int d = i*8192 + t*16;
            const int row = i*8 + w;
            const int colb = (l*16) ^ ((row&7)<<4);
            const size_t g = kb + (size_t)row*1024 + colb;
            __builtin_amdgcn_global_load_lds(AS1((const char*)kTh + g), AS3((char*)dh + d), 16, 0, 0);
            __builtin_amdgcn_global_load_lds(AS1((const char*)kTl + g), AS3((char*)dl + d), 16, 0, 0);
        }
    };
    auto loadV = [&](int mt, bf16x8* vf){
        const size_t vcol = (size_t)mt*32 + lg*8;
        #pragma unroll
        for (int ac=0;ac<4;ac++)
            vf[ac] = *(const bf16x8*)(vB + ((size_t)b*C_ + cw + ac*16 + lr)*N_ + vcol);
    };
    // SC2 = sqrt(512)*log2(e) folded into the S write; softmax in exp2 domain
    const float SC2 = 32.6444622284f;
    auto qk_tile = [&](const unsigned short* kh, const unsigned short* kl){
        f32x4 s0 = (f32x4){0.f,0.f,0.f,0.f}, s1 = s0;
        const int krow = fn*16 + lr;
        const int rbase = krow*1024;
        const int swz = (krow&7)<<4;
        __builtin_amdgcn_s_setprio(1);
        #pragma unroll
        for (int kc=0;kc<8;kc++){
            const int o = rbase + ((ch*512 + kc*64 + lg*16) ^ swz);
            bf16x8 kf  = *(const bf16x8*)((const char*)kh + o);
            bf16x8 kfl = *(const bf16x8*)((const char*)kl + o);
            s0 = mfma16(qh[0][kc], kf,  s0);
            s0 = mfma16(ql[0][kc], kf,  s0);
            s0 = mfma16(qh[0][kc], kfl, s0);
            s1 = mfma16(qh[1][kc], kf,  s1);
            s1 = mfma16(ql[1][kc], kf,  s1);
            s1 = mfma16(qh[1][kc], kfl, s1);
        }
        __builtin_amdgcn_s_setprio(0);
        #pragma unroll
        for (int r=0;r<4;r++){
            Sb[ch][fm2*32 +      lg*4 + r][fn*16 + lr] = s0[r]*SC2;
            Sb[ch][fm2*32 + 16 + lg*4 + r][fn*16 + lr] = s1[r]*SC2;
        }
    };

    bf16x8 vf[4];
    // prologue: V(0), K(0), K(1) all in flight; drain through K(0)+V(0), keep K(1)
    loadV(0, vf);
    stage(0, khA, klA);
    stage(1, khB, klB);
    asm volatile("s_waitcnt vmcnt(8)" ::: "memory");
    __builtin_amdgcn_s_barrier();
    qk_tile(khA, klA);
    asm volatile("s_waitcnt lgkmcnt(0)" ::: "memory");
    __builtin_amdgcn_s_barrier();

    for (int mt=0; mt<128; mt++){
        // ---- phase1: stage(mt+2) issue + online softmax (exp2) for tile mt ----
        if (mt < 126) stage(mt+2, (mt&1) ? khB : khA, (mt&1) ? klB : klA);
        {
            const int row = t>>3, j = t&7;
            f32x4 u0 = *(const f32x4*)&Sb[0][row][j*4];
            f32x4 u1 = *(const f32x4*)&Sb[1][row][j*4];
            float a0 = u0[0] + u1[0];
            float a1 = u0[1] + u1[1];
            float a2 = u0[2] + u1[2];
            float a3 = u0[3] + u1[3];
            float mx = fmaxf(fmaxf(a0,a1), fmaxf(a2,a3));
            mx = fmaxf(mx, __shfl_xor(mx, 1, 8));
            mx = fmaxf(mx, __shfl_xor(mx, 2, 8));
            mx = fmaxf(mx, __shfl_xor(mx, 4, 8));
            const float mprev = rowM[row];
            const float mnew = fmaxf(mprev, mx);
            float p0 = exp2f(a0 - mnew), p1 = exp2f(a1 - mnew);
            float p2 = exp2f(a2 - mnew), p3 = exp2f(a3 - mnew);
            float ps = (p0+p1)+(p2+p3);
            ps += __shfl_xor(ps, 1, 8);
            ps += __shfl_xor(ps, 2, 8);
            ps += __shfl_xor(ps, 4, 8);
            ushort4 pk; pk.x=f2bf(p0); pk.y=f2bf(p1); pk.z=f2bf(p2); pk.w=f2bf(p3);
            char* pw = (char*)Pb + row*64 + ((((j>>1) + (row>>1)) & 3)<<4) + ((j&1)<<3);
            *(ushort4*)pw = pk;
            if (j==0){
                float f = exp2f(mprev - mnew);
                rowF[row] = f;
                rowS[row] = rowS[row]*f + ps;
                rowM[row] = mnew;
            }
        }
        // counted drain: complete K(mt+1) DMA + V(mt) loads; keep K(mt+2)'s 8 loads in flight
        if (mt < 126) asm volatile("s_waitcnt vmcnt(8) lgkmcnt(0)" ::: "memory");
        else          asm volatile("s_waitcnt vmcnt(0) lgkmcnt(0)" ::: "memory");
        __builtin_amdgcn_s_barrier();

        // ---- phase2: PV(mt) | loadV(mt+1) | QK(mt+1) ----
        __builtin_amdgcn_s_setprio(1);
        {
            float frv[4][4]; bool need = false;
            #pragma unroll
            for (int am=0;am<4;am++)
                #pragma unroll
                for (int r=0;r<4;r++){
                    frv[am][r] = rowF[am*16 + lg*4 + r];
                    need |= (frv[am][r] != 1.0f);
                }
            if (__any(need)){
                #pragma unroll
                for (int am=0;am<4;am++)
                    #pragma unroll
                    for (int ac=0;ac<4;ac++)
                        #pragma unroll
                        for (int r=0;r<4;r++) accO[am][ac][r] *= frv[am][r];
            }
            bf16x8 pa[4];
            #pragma unroll
            for (int am=0;am<4;am++){
                const int prow = am*16 + lr;
                pa[am] = *(const bf16x8*)((const char*)Pb + prow*64 + (((lg + (prow>>1)) & 3)<<4));
            }
            #pragma unroll
            for (int ac=0;ac<4;ac++)
                #pragma unroll
                for (int am=0;am<4;am++)
                    accO[am][ac] = mfma16(pa[am], vf[ac], accO[am][ac]);
        }
        if (mt < 127){
            loadV(mt+1, vf);
            qk_tile(((mt+1)&1) ? khB : khA, ((mt+1)&1) ? klB : klA);
        }
        __builtin_amdgcn_s_setprio(0);
        asm volatile("s_waitcnt lgkmcnt(0)" ::: "memory");
        __builtin_amdgcn_s_barrier();
    }

    // ---- normalize + write aoT[B][N][C] ----
    #pragma unroll
    for (int am=0;am<4;am++)
        #pragma unroll
        for (int r=0;r<4;r++){
            const int n = am*16 + lg*4 + r;
            const float inv = 1.0f / rowS[n];
            #pragma unroll
            for (int ac=0;ac<4;ac++)
                aoT[((size_t)b*N_ + n0 + n)*C_ + cw + ac*16 + lr] = f2bf(accO[am][ac][r]*inv);
        }
}

extern "C" void kernel_launch(void* const* d_in, const int* in_sizes, int n_in,
                              void* d_out, int out_size, void* d_ws, size_t ws_size,
                              hipStream_t stream)
{
    const float* x   = (const float*)d_in[0];
    const float* gnw = (const float*)d_in[1];
    const float* gnb = (const float*)d_in[2];
    const float* wq  = (const float*)d_in[3];
    const float* bq  = (const float*)d_in[4];
    const float* wk  = (const float*)d_in[5];
    const float* bk  = (const float*)d_in[6];
    const float* wv  = (const float*)d_in[7];
    const float* bv  = (const float*)d_in[8];
    const float* wp  = (const float*)d_in[9];
    const float* bp  = (const float*)d_in[10];
    float* out = (float*)d_out;

    char* ws = (char*)d_ws;
    size_t off = 0;
    auto alloc = [&](size_t bytes)->char*{
        char* p = ws + off; off += (bytes + 255) & ~(size_t)255; return p;
    };
    const size_t WB = (size_t)C_*C_*2;
    const size_t TB = (size_t)B_*N_*C_*2;
    unsigned short* wqh = (unsigned short*)alloc(WB);
    unsigned short* wql = (unsigned short*)alloc(WB);
    unsigned short* wkh = (unsigned short*)alloc(WB);
    unsigned short* wkl = (unsigned short*)alloc(WB);
    unsigned short* wvh = (unsigned short*)alloc(WB);
    unsigned short* wvl = (unsigned short*)alloc(WB);
    unsigned short* wph = (unsigned short*)alloc(WB);
    unsigned short* wpl = (unsigned short*)alloc(WB);
    unsigned short* hTh = (unsigned short*)alloc(TB);
    unsigned short* hTl = (unsigned short*)alloc(TB);
    unsigned short* qTh = (unsigned short*)alloc(TB);
    unsigned short* qTl = (unsigned short*)alloc(TB);
    unsigned short* kTh = (unsigned short*)alloc(TB);
    unsigned short* kTl = (unsigned short*)alloc(TB);
    unsigned short* vb  = (unsigned short*)alloc(TB);
    unsigned short* ao  = (unsigned short*)alloc(TB);
    float2* part  = (float2*)alloc(8*64*sizeof(float2));
    float2* stats = (float2*)alloc(8*sizeof(float2));

    split_w<<<256, 256, 0, stream>>>(wq, wqh, wql);
    split_w<<<256, 256, 0, stream>>>(wk, wkh, wkl);
    split_w<<<256, 256, 0, stream>>>(wv, wvh, wvl);
    split_w<<<256, 256, 0, stream>>>(wp, wph, wpl);
    gn_part<<<dim3(64, 8), 256, 0, stream>>>(x, part);
    gn_fin<<<8, 64, 0, stream>>>(part, stats);
    gn_apply<<<dim3(128, 16, B_), 256, 0, stream>>>(x, gnw, gnb, stats, hTh, hTl);
    conv_gemm<3,0><<<dim3(32,4,B_), 256, 0, stream>>>(wqh,wql,hTh,hTl,bq, qTh,qTl,nullptr,nullptr);
    conv_gemm<3,0><<<dim3(32,4,B_), 256, 0, stream>>>(wkh,wkl,hTh,hTl,bk, kTh,kTl,nullptr,nullptr);
    conv_gemm<1,1><<<dim3(32,4,B_), 256, 0, stream>>>(wvh,wvl,hTh,hTl,bv, vb,nullptr,nullptr,nullptr);
    attn_flash12<<<dim3(256), 512, 0, stream>>>(qTh,qTl,kTh,kTl,vb,ao);
    conv_gemm<1,2><<<dim3(32,4,B_), 256, 0, stream>>>(wph,wpl,ao,nullptr,bp, nullptr,nullptr,out,x);
}